// Round 1
// baseline (1531.273 us; speedup 1.0000x reference)
//
#include <hip/hip_runtime.h>

#define D 128

// T = R @ W  for one matrix (nrel x D) @ (D x D)
__global__ void transform_kernel(const float* __restrict__ R, const float* __restrict__ W,
                                 float* __restrict__ T, int nrel) {
    __shared__ float row[D];
    int r = blockIdx.x;
    if (r >= nrel) return;
    int t = threadIdx.x; // 0..127
    row[t] = R[r * D + t];
    __syncthreads();
    float acc = 0.f;
#pragma unroll 8
    for (int k = 0; k < D; ++k) acc += row[k] * W[k * D + t];
    T[r * D + t] = acc;
}

// degree counts: rows[0:E] -> deg_in, rows[E:2E] -> deg_out
__global__ void degree_kernel(const int* __restrict__ rows, int E,
                              float* __restrict__ deg_in, float* __restrict__ deg_out) {
    int i = blockIdx.x * blockDim.x + threadIdx.x;
    int stride = gridDim.x * blockDim.x;
    int total = 2 * E;
    for (; i < total; i += stride) {
        int r = rows[i];
        if (i < E) atomicAdd(&deg_in[r], 1.0f);
        else       atomicAdd(&deg_out[r], 1.0f);
    }
}

// wave-per-edge scatter: out[row] += 0.5*norm * T[type]
__global__ void scatter_kernel(const int* __restrict__ rows, const int* __restrict__ cols,
                               const int* __restrict__ etype,
                               const float* __restrict__ deg_in, const float* __restrict__ deg_out,
                               const float* __restrict__ T_in, const float* __restrict__ T_out,
                               float* __restrict__ out, int E) {
    int wave = (blockIdx.x * blockDim.x + threadIdx.x) >> 6;
    int lane = threadIdx.x & 63;
    int nwaves = (gridDim.x * blockDim.x) >> 6;
    int total = 2 * E;
    for (int e = wave; e < total; e += nwaves) {
        bool first = (e < E);
        int row = rows[e];
        int col = cols[e];
        int t = etype[e];
        const float* deg = first ? deg_in : deg_out;
        const float* T = first ? T_in : T_out;
        float dr = deg[row];
        float dc = deg[col];
        float norm = (dr > 0.f ? rsqrtf(dr) : 0.f) * (dc > 0.f ? rsqrtf(dc) : 0.f);
        float c = 0.5f * norm;
        if (c != 0.f) {
            float v0 = c * T[t * D + lane];
            float v1 = c * T[t * D + 64 + lane];
            long base = (long)row * D;
            atomicAdd(&out[base + lane], v0);
            atomicAdd(&out[base + 64 + lane], v1);
        }
    }
}

// per-feature sum and sum-of-squares over nent rows (blockDim = 128)
__global__ void bn_stats_kernel(const float* __restrict__ h, int nent,
                                float* __restrict__ sums, float* __restrict__ sumsq) {
    int col = threadIdx.x;
    float s = 0.f, s2 = 0.f;
    for (int r = blockIdx.x; r < nent; r += gridDim.x) {
        float v = h[(long)r * D + col];
        s += v;
        s2 += v * v;
    }
    atomicAdd(&sums[col], s);
    atomicAdd(&sumsq[col], s2);
}

__global__ void bn_apply_kernel(float* __restrict__ h,
                                const float* __restrict__ sums, const float* __restrict__ sumsq,
                                const float* __restrict__ gamma, const float* __restrict__ beta,
                                int nent) {
    long total = (long)nent * D;
    long stride = (long)gridDim.x * blockDim.x;
    float inv_n = 1.0f / (float)nent;
    for (long i = (long)blockIdx.x * blockDim.x + threadIdx.x; i < total; i += stride) {
        int col = (int)(i & (D - 1));
        float mean = sums[col] * inv_n;
        float var = sumsq[col] * inv_n - mean * mean;
        float istd = rsqrtf(var + 1e-5f);
        float v = h[i];
        h[i] = tanhf((v - mean) * istd * gamma[col] + beta[col]);
    }
}

extern "C" void kernel_launch(void* const* d_in, const int* in_sizes, int n_in,
                              void* d_out, int out_size, void* d_ws, size_t ws_size,
                              hipStream_t stream) {
    const float* rel_embed     = (const float*)d_in[0];
    const float* rel_embed_in  = (const float*)d_in[1];
    const float* rel_embed_out = (const float*)d_in[2];
    const float* w_in          = (const float*)d_in[3];
    const float* w_out         = (const float*)d_in[4];
    const float* bn_gamma      = (const float*)d_in[5];
    const float* bn_beta       = (const float*)d_in[6];
    const int*   edge_index    = (const int*)d_in[7];
    const int*   edge_type     = (const int*)d_in[8];

    const int nrel = in_sizes[0] / D;          // 500
    const int E2   = in_sizes[8];              // 3,000,000
    const int E    = E2 / 2;                   // 1,500,000
    const int nent = (out_size - in_sizes[0]) / D;  // 200,000

    float* out = (float*)d_out;                // [nent*D] res, then [nrel*D] rel_embed

    // workspace layout (floats)
    float* ws      = (float*)d_ws;
    float* deg_in  = ws;                       // nent
    float* deg_out = deg_in + nent;            // nent
    float* T_in    = deg_out + nent;           // nrel*D
    float* T_out   = T_in + (long)nrel * D;    // nrel*D
    float* sums    = T_out + (long)nrel * D;   // D
    float* sumsq   = sums + D;                 // D

    // zero accumulators (graph-capture-safe async memsets)
    hipMemsetAsync(out, 0, (size_t)nent * D * sizeof(float), stream);
    hipMemsetAsync(deg_in, 0, (size_t)2 * nent * sizeof(float), stream);
    hipMemsetAsync(sums, 0, (size_t)2 * D * sizeof(float), stream);

    // relation transforms (tiny)
    transform_kernel<<<nrel, D, 0, stream>>>(rel_embed_in, w_in, T_in, nrel);
    transform_kernel<<<nrel, D, 0, stream>>>(rel_embed_out, w_out, T_out, nrel);

    // degrees
    degree_kernel<<<2048, 256, 0, stream>>>(edge_index, E, deg_in, deg_out);

    // scatter-accumulate h into out
    const int* rows = edge_index;        // edge_index[0, :]
    const int* cols = edge_index + E2;   // edge_index[1, :]
    scatter_kernel<<<2048, 256, 0, stream>>>(rows, cols, edge_type,
                                             deg_in, deg_out, T_in, T_out, out, E);

    // batchnorm stats + apply (tanh), in place on out
    bn_stats_kernel<<<1024, D, 0, stream>>>(out, nent, sums, sumsq);
    bn_apply_kernel<<<2048, 256, 0, stream>>>(out, sums, sumsq, bn_gamma, bn_beta, nent);

    // passthrough rel_embed as second tuple output
    hipMemcpyAsync(out + (size_t)nent * D, rel_embed,
                   (size_t)nrel * D * sizeof(float), hipMemcpyDeviceToDevice, stream);
}

// Round 2
// 1160.386 us; speedup vs baseline: 1.3196x; 1.3196x over previous
//
#include <hip/hip_runtime.h>

#define D 128

// ---------------- shared small kernels ----------------

// T = R @ W  for one matrix (nrel x D) @ (D x D)
__global__ void transform_kernel(const float* __restrict__ R, const float* __restrict__ W,
                                 float* __restrict__ T, int nrel) {
    __shared__ float row[D];
    int r = blockIdx.x;
    if (r >= nrel) return;
    int t = threadIdx.x; // 0..127
    row[t] = R[r * D + t];
    __syncthreads();
    float acc = 0.f;
#pragma unroll 8
    for (int k = 0; k < D; ++k) acc += row[k] * W[k * D + t];
    T[r * D + t] = acc;
}

// degree counts: rows[0:E] -> deg_in, rows[E:2E] -> deg_out
__global__ void degree_kernel(const int* __restrict__ rows, int E,
                              float* __restrict__ deg_in, float* __restrict__ deg_out) {
    int i = blockIdx.x * blockDim.x + threadIdx.x;
    int stride = gridDim.x * blockDim.x;
    int total = 2 * E;
    for (; i < total; i += stride) {
        int r = rows[i];
        if (i < E) atomicAdd(&deg_in[r], 1.0f);
        else       atomicAdd(&deg_out[r], 1.0f);
    }
}

// ---------------- sort-based fast path ----------------

// single-block exclusive scan of cnt[row] = deg_in[row]+deg_out[row] -> base[0..nent]
__global__ void scan_kernel(const float* __restrict__ deg_in, const float* __restrict__ deg_out,
                            unsigned int* __restrict__ base, int nent) {
    const int T = 1024;
    int t = threadIdx.x;
    int chunk = (nent + T - 1) / T;
    int s = t * chunk;
    int e = s + chunk; if (e > nent) e = nent;
    unsigned int local = 0;
    for (int i = s; i < e; ++i) local += (unsigned int)(deg_in[i] + deg_out[i] + 0.5f);
    __shared__ unsigned int ls[T];
    ls[t] = local;
    __syncthreads();
    for (int off = 1; off < T; off <<= 1) {
        unsigned int add = (t >= off) ? ls[t - off] : 0u;
        __syncthreads();
        ls[t] += add;
        __syncthreads();
    }
    unsigned int run = (t > 0) ? ls[t - 1] : 0u; // exclusive prefix
    for (int i = s; i < e; ++i) {
        base[i] = run;
        run += (unsigned int)(deg_in[i] + deg_out[i] + 0.5f);
    }
    if (t == T - 1) base[nent] = ls[T - 1];
}

// bucket-scatter: for each edge, payload[pos] = (coeff, table_row)
__global__ void build_kernel(const int* __restrict__ rows, const int* __restrict__ cols,
                             const int* __restrict__ etype,
                             const float* __restrict__ deg_in, const float* __restrict__ deg_out,
                             const unsigned int* __restrict__ base, unsigned int* __restrict__ cursor,
                             uint2* __restrict__ payload, int E, int nrel) {
    int i = blockIdx.x * blockDim.x + threadIdx.x;
    int stride = gridDim.x * blockDim.x;
    int total = 2 * E;
    for (; i < total; i += stride) {
        bool first = (i < E);
        int row = rows[i];
        int col = cols[i];
        int t = etype[i];
        const float* deg = first ? deg_in : deg_out;
        float dr = deg[row];
        float dc = deg[col];
        float norm = (dr > 0.f ? rsqrtf(dr) : 0.f) * (dc > 0.f ? rsqrtf(dc) : 0.f);
        float c = 0.5f * norm;
        unsigned int pos = base[row] + atomicAdd(&cursor[row], 1u);
        payload[pos] = make_uint2(__float_as_uint(c), (unsigned int)(t + (first ? 0 : nrel)));
    }
}

// wave-per-row gather-accumulate + fused BN partial stats
__global__ __launch_bounds__(256) void accum_kernel(
        const unsigned int* __restrict__ base, const uint2* __restrict__ payload,
        const float* __restrict__ T_all, float* __restrict__ out,
        float* __restrict__ sums, float* __restrict__ sumsq, int nent) {
    int wave = (blockIdx.x * blockDim.x + threadIdx.x) >> 6;
    int lane = threadIdx.x & 63;
    int nw = (gridDim.x * blockDim.x) >> 6;
    float s0 = 0.f, q0 = 0.f, s1 = 0.f, q1 = 0.f;
    for (int row = wave; row < nent; row += nw) {
        unsigned int b = base[row], en = base[row + 1];
        float a0 = 0.f, a1 = 0.f;
        for (unsigned int i = b; i < en; ++i) {
            uint2 p = payload[i];                 // wave-uniform address -> broadcast
            float c = __uint_as_float(p.x);
            const float* Tr = T_all + (size_t)p.y * D;
            a0 += c * Tr[lane];
            a1 += c * Tr[64 + lane];
        }
        size_t o = (size_t)row * D;
        out[o + lane] = a0;
        out[o + 64 + lane] = a1;
        s0 += a0; q0 += a0 * a0;
        s1 += a1; q1 += a1 * a1;
    }
    __shared__ float ls[D], lq[D];
    if (threadIdx.x < D) { ls[threadIdx.x] = 0.f; lq[threadIdx.x] = 0.f; }
    __syncthreads();
    atomicAdd(&ls[lane], s0);       atomicAdd(&ls[lane + 64], s1);
    atomicAdd(&lq[lane], q0);       atomicAdd(&lq[lane + 64], q1);
    __syncthreads();
    if (threadIdx.x < D) {
        atomicAdd(&sums[threadIdx.x], ls[threadIdx.x]);
        atomicAdd(&sumsq[threadIdx.x], lq[threadIdx.x]);
    }
}

// ---------------- fallback (atomic) path kernels ----------------

__global__ void scatter_kernel(const int* __restrict__ rows, const int* __restrict__ cols,
                               const int* __restrict__ etype,
                               const float* __restrict__ deg_in, const float* __restrict__ deg_out,
                               const float* __restrict__ T_in, const float* __restrict__ T_out,
                               float* __restrict__ out, int E) {
    int wave = (blockIdx.x * blockDim.x + threadIdx.x) >> 6;
    int lane = threadIdx.x & 63;
    int nwaves = (gridDim.x * blockDim.x) >> 6;
    int total = 2 * E;
    for (int e = wave; e < total; e += nwaves) {
        bool first = (e < E);
        int row = rows[e];
        int col = cols[e];
        int t = etype[e];
        const float* deg = first ? deg_in : deg_out;
        const float* T = first ? T_in : T_out;
        float dr = deg[row];
        float dc = deg[col];
        float norm = (dr > 0.f ? rsqrtf(dr) : 0.f) * (dc > 0.f ? rsqrtf(dc) : 0.f);
        float c = 0.5f * norm;
        if (c != 0.f) {
            float v0 = c * T[t * D + lane];
            float v1 = c * T[t * D + 64 + lane];
            long b = (long)row * D;
            atomicAdd(&out[b + lane], v0);
            atomicAdd(&out[b + 64 + lane], v1);
        }
    }
}

__global__ void bn_stats_kernel(const float* __restrict__ h, int nent,
                                float* __restrict__ sums, float* __restrict__ sumsq) {
    int col = threadIdx.x;
    float s = 0.f, s2 = 0.f;
    for (int r = blockIdx.x; r < nent; r += gridDim.x) {
        float v = h[(long)r * D + col];
        s += v;
        s2 += v * v;
    }
    atomicAdd(&sums[col], s);
    atomicAdd(&sumsq[col], s2);
}

// ---------------- BN apply (both paths) ----------------

__global__ void bn_apply_kernel(float* __restrict__ h,
                                const float* __restrict__ sums, const float* __restrict__ sumsq,
                                const float* __restrict__ gamma, const float* __restrict__ beta,
                                int nent) {
    long total = ((long)nent * D) / 4;     // in float4 units
    long stride = (long)gridDim.x * blockDim.x;
    float inv_n = 1.0f / (float)nent;
    float4* h4 = (float4*)h;
    for (long i = (long)blockIdx.x * blockDim.x + threadIdx.x; i < total; i += stride) {
        int c0 = (int)((i * 4) & (D - 1));
        float4 v = h4[i];
        float r[4] = {v.x, v.y, v.z, v.w};
#pragma unroll
        for (int j = 0; j < 4; ++j) {
            int col = c0 + j;
            float mean = sums[col] * inv_n;
            float var = sumsq[col] * inv_n - mean * mean;
            float istd = rsqrtf(var + 1e-5f);
            r[j] = tanhf((r[j] - mean) * istd * gamma[col] + beta[col]);
        }
        h4[i] = make_float4(r[0], r[1], r[2], r[3]);
    }
}

extern "C" void kernel_launch(void* const* d_in, const int* in_sizes, int n_in,
                              void* d_out, int out_size, void* d_ws, size_t ws_size,
                              hipStream_t stream) {
    const float* rel_embed     = (const float*)d_in[0];
    const float* rel_embed_in  = (const float*)d_in[1];
    const float* rel_embed_out = (const float*)d_in[2];
    const float* w_in          = (const float*)d_in[3];
    const float* w_out         = (const float*)d_in[4];
    const float* bn_gamma      = (const float*)d_in[5];
    const float* bn_beta       = (const float*)d_in[6];
    const int*   edge_index    = (const int*)d_in[7];
    const int*   edge_type     = (const int*)d_in[8];

    const int nrel = in_sizes[0] / D;               // 500
    const int E2   = in_sizes[8];                   // 3,000,000
    const int E    = E2 / 2;                        // 1,500,000
    const int nent = (out_size - in_sizes[0]) / D;  // 200,000

    float* out = (float*)d_out;  // [nent*D] res, then [nrel*D] rel_embed

    const int* rows = edge_index;        // edge_index[0, :]
    const int* cols = edge_index + E2;   // edge_index[1, :]

    // ---- workspace layout (fast path) ----
    // [deg_in | deg_out | cursor | sums | sumsq]  <- zeroed in one memset
    // [base | T_all | payload]
    float*        ws      = (float*)d_ws;
    float*        deg_in  = ws;                                   // nent
    float*        deg_out = deg_in + nent;                        // nent
    unsigned int* cursor  = (unsigned int*)(deg_out + nent);      // nent
    float*        sums    = (float*)(cursor + nent);              // D
    float*        sumsq   = sums + D;                             // D
    unsigned int* base    = (unsigned int*)(sumsq + D);           // nent+1
    float*        T_all   = (float*)(base + nent + 1);            // 2*nrel*D
    uintptr_t pal = ((uintptr_t)(T_all + (size_t)2 * nrel * D) + 7) & ~(uintptr_t)7;
    uint2*        payload = (uint2*)pal;                          // 2E
    size_t needed = (pal + (size_t)E2 * sizeof(uint2)) - (uintptr_t)d_ws;

    if (needed <= ws_size) {
        // ---------- fast sort-based path ----------
        float* T_in  = T_all;
        float* T_out = T_all + (size_t)nrel * D;

        hipMemsetAsync(deg_in, 0, ((size_t)3 * nent + 2 * D) * sizeof(float), stream);

        transform_kernel<<<nrel, D, 0, stream>>>(rel_embed_in,  w_in,  T_in,  nrel);
        transform_kernel<<<nrel, D, 0, stream>>>(rel_embed_out, w_out, T_out, nrel);

        degree_kernel<<<2048, 256, 0, stream>>>(edge_index, E, deg_in, deg_out);
        scan_kernel<<<1, 1024, 0, stream>>>(deg_in, deg_out, base, nent);
        build_kernel<<<2048, 256, 0, stream>>>(rows, cols, edge_type, deg_in, deg_out,
                                               base, cursor, payload, E, nrel);
        accum_kernel<<<2048, 256, 0, stream>>>(base, payload, T_all, out, sums, sumsq, nent);
        bn_apply_kernel<<<4096, 256, 0, stream>>>(out, sums, sumsq, bn_gamma, bn_beta, nent);
    } else {
        // ---------- fallback atomic path ----------
        float* f_deg_in  = ws;
        float* f_deg_out = f_deg_in + nent;
        float* f_T_in    = f_deg_out + nent;
        float* f_T_out   = f_T_in + (size_t)nrel * D;
        float* f_sums    = f_T_out + (size_t)nrel * D;
        float* f_sumsq   = f_sums + D;

        hipMemsetAsync(out, 0, (size_t)nent * D * sizeof(float), stream);
        hipMemsetAsync(f_deg_in, 0, (size_t)2 * nent * sizeof(float), stream);
        hipMemsetAsync(f_sums, 0, (size_t)2 * D * sizeof(float), stream);

        transform_kernel<<<nrel, D, 0, stream>>>(rel_embed_in,  w_in,  f_T_in,  nrel);
        transform_kernel<<<nrel, D, 0, stream>>>(rel_embed_out, w_out, f_T_out, nrel);
        degree_kernel<<<2048, 256, 0, stream>>>(edge_index, E, f_deg_in, f_deg_out);
        scatter_kernel<<<2048, 256, 0, stream>>>(rows, cols, edge_type, f_deg_in, f_deg_out,
                                                 f_T_in, f_T_out, out, E);
        bn_stats_kernel<<<1024, D, 0, stream>>>(out, nent, f_sums, f_sumsq);
        bn_apply_kernel<<<4096, 256, 0, stream>>>(out, f_sums, f_sumsq, bn_gamma, bn_beta, nent);
    }

    // passthrough rel_embed as second tuple output
    hipMemcpyAsync(out + (size_t)nent * D, rel_embed,
                   (size_t)nrel * D * sizeof(float), hipMemcpyDeviceToDevice, stream);
}

// Round 3
// 637.640 us; speedup vs baseline: 2.4015x; 1.8198x over previous
//
#include <hip/hip_runtime.h>

#define D 128
#define TILE 1024

// ---------------- shared small kernels ----------------

// T = R @ W  for one matrix (nrel x D) @ (D x D)
__global__ void transform_kernel(const float* __restrict__ R, const float* __restrict__ W,
                                 float* __restrict__ T, int nrel) {
    __shared__ float row[D];
    int r = blockIdx.x;
    if (r >= nrel) return;
    int t = threadIdx.x; // 0..127
    row[t] = R[r * D + t];
    __syncthreads();
    float acc = 0.f;
#pragma unroll 8
    for (int k = 0; k < D; ++k) acc += row[k] * W[k * D + t];
    T[r * D + t] = acc;
}

// degree counts: rows[0:E] -> deg_in, rows[E:2E] -> deg_out
__global__ void degree_kernel(const int* __restrict__ rows, int E,
                              float* __restrict__ deg_in, float* __restrict__ deg_out) {
    int i = blockIdx.x * blockDim.x + threadIdx.x;
    int stride = gridDim.x * blockDim.x;
    int total = 2 * E;
    for (; i < total; i += stride) {
        int r = rows[i];
        if (i < E) atomicAdd(&deg_in[r], 1.0f);
        else       atomicAdd(&deg_out[r], 1.0f);
    }
}

// ---------------- device-wide scan (3 kernels) ----------------

// per-tile sum of counts (TILE elems per block of 256 threads)
__global__ __launch_bounds__(256) void tile_sum_kernel(
        const float* __restrict__ deg_in, const float* __restrict__ deg_out,
        unsigned int* __restrict__ tile_sums, int nent) {
    int tid = threadIdx.x;
    int i0 = blockIdx.x * TILE + tid * 4;
    unsigned int s = 0;
#pragma unroll
    for (int k = 0; k < 4; ++k) {
        int i = i0 + k;
        if (i < nent) s += (unsigned int)(deg_in[i] + deg_out[i] + 0.5f);
    }
    __shared__ unsigned int ls[256];
    ls[tid] = s;
    __syncthreads();
    for (int off = 128; off >= 1; off >>= 1) {
        if (tid < off) ls[tid] += ls[tid + off];
        __syncthreads();
    }
    if (tid == 0) tile_sums[blockIdx.x] = ls[0];
}

// single-block exclusive scan of tile sums (ntiles <= 1024); also writes base[nent]=total
__global__ void scan_tiles_kernel(const unsigned int* __restrict__ tile_sums,
                                  unsigned int* __restrict__ tile_off,
                                  unsigned int* __restrict__ base, int ntiles, int nent) {
    int t = threadIdx.x; // blockDim = 1024
    __shared__ unsigned int ls[1024];
    unsigned int v = (t < ntiles) ? tile_sums[t] : 0u;
    ls[t] = v;
    __syncthreads();
    for (int off = 1; off < 1024; off <<= 1) {
        unsigned int add = (t >= off) ? ls[t - off] : 0u;
        __syncthreads();
        ls[t] += add;
        __syncthreads();
    }
    if (t < ntiles) tile_off[t] = ls[t] - v; // exclusive
    if (t == 1023) base[nent] = ls[1023];    // grand total (pads are 0)
}

// per-tile block scan + tile offset -> base[i]
__global__ __launch_bounds__(256) void base_write_kernel(
        const float* __restrict__ deg_in, const float* __restrict__ deg_out,
        const unsigned int* __restrict__ tile_off,
        unsigned int* __restrict__ base, int nent) {
    int tid = threadIdx.x;
    int i0 = blockIdx.x * TILE + tid * 4;
    unsigned int c[4];
#pragma unroll
    for (int k = 0; k < 4; ++k) {
        int i = i0 + k;
        c[k] = (i < nent) ? (unsigned int)(deg_in[i] + deg_out[i] + 0.5f) : 0u;
    }
    unsigned int s = c[0] + c[1] + c[2] + c[3];
    __shared__ unsigned int ls[256];
    ls[tid] = s;
    __syncthreads();
    for (int off = 1; off < 256; off <<= 1) {
        unsigned int add = (tid >= off) ? ls[tid - off] : 0u;
        __syncthreads();
        ls[tid] += add;
        __syncthreads();
    }
    unsigned int run = (tid > 0 ? ls[tid - 1] : 0u) + tile_off[blockIdx.x];
#pragma unroll
    for (int k = 0; k < 4; ++k) {
        int i = i0 + k;
        if (i < nent) base[i] = run;
        run += c[k];
    }
}

// ---------------- sort-based fast path ----------------

// bucket-scatter: for each edge, payload[pos] = (coeff, table_row)
__global__ void build_kernel(const int* __restrict__ rows, const int* __restrict__ cols,
                             const int* __restrict__ etype,
                             const float* __restrict__ deg_in, const float* __restrict__ deg_out,
                             const unsigned int* __restrict__ base, unsigned int* __restrict__ cursor,
                             uint2* __restrict__ payload, int E, int nrel) {
    int i = blockIdx.x * blockDim.x + threadIdx.x;
    int stride = gridDim.x * blockDim.x;
    int total = 2 * E;
    for (; i < total; i += stride) {
        bool first = (i < E);
        int row = rows[i];
        int col = cols[i];
        int t = etype[i];
        const float* deg = first ? deg_in : deg_out;
        float dr = deg[row];
        float dc = deg[col];
        float norm = (dr > 0.f ? rsqrtf(dr) : 0.f) * (dc > 0.f ? rsqrtf(dc) : 0.f);
        float c = 0.5f * norm;
        unsigned int pos = base[row] + atomicAdd(&cursor[row], 1u);
        payload[pos] = make_uint2(__float_as_uint(c), (unsigned int)(t + (first ? 0 : nrel)));
    }
}

// wave-per-row gather-accumulate + fused BN partial stats
__global__ __launch_bounds__(256) void accum_kernel(
        const unsigned int* __restrict__ base, const uint2* __restrict__ payload,
        const float* __restrict__ T_all, float* __restrict__ out,
        float* __restrict__ sums, float* __restrict__ sumsq, int nent) {
    int wave = (blockIdx.x * blockDim.x + threadIdx.x) >> 6;
    int lane = threadIdx.x & 63;
    int nw = (gridDim.x * blockDim.x) >> 6;
    float s0 = 0.f, q0 = 0.f, s1 = 0.f, q1 = 0.f;
    for (int row = wave; row < nent; row += nw) {
        unsigned int b = base[row], en = base[row + 1];
        float a0 = 0.f, a1 = 0.f;
        for (unsigned int i = b; i < en; ++i) {
            uint2 p = payload[i];                 // wave-uniform address -> broadcast
            float c = __uint_as_float(p.x);
            const float* Tr = T_all + (size_t)p.y * D;
            a0 += c * Tr[lane];
            a1 += c * Tr[64 + lane];
        }
        size_t o = (size_t)row * D;
        out[o + lane] = a0;
        out[o + 64 + lane] = a1;
        s0 += a0; q0 += a0 * a0;
        s1 += a1; q1 += a1 * a1;
    }
    __shared__ float ls[D], lq[D];
    if (threadIdx.x < D) { ls[threadIdx.x] = 0.f; lq[threadIdx.x] = 0.f; }
    __syncthreads();
    atomicAdd(&ls[lane], s0);       atomicAdd(&ls[lane + 64], s1);
    atomicAdd(&lq[lane], q0);       atomicAdd(&lq[lane + 64], q1);
    __syncthreads();
    if (threadIdx.x < D) {
        atomicAdd(&sums[threadIdx.x], ls[threadIdx.x]);
        atomicAdd(&sumsq[threadIdx.x], lq[threadIdx.x]);
    }
}

// ---------------- fallback (atomic) path kernels ----------------

__global__ void scatter_kernel(const int* __restrict__ rows, const int* __restrict__ cols,
                               const int* __restrict__ etype,
                               const float* __restrict__ deg_in, const float* __restrict__ deg_out,
                               const float* __restrict__ T_in, const float* __restrict__ T_out,
                               float* __restrict__ out, int E) {
    int wave = (blockIdx.x * blockDim.x + threadIdx.x) >> 6;
    int lane = threadIdx.x & 63;
    int nwaves = (gridDim.x * blockDim.x) >> 6;
    int total = 2 * E;
    for (int e = wave; e < total; e += nwaves) {
        bool first = (e < E);
        int row = rows[e];
        int col = cols[e];
        int t = etype[e];
        const float* deg = first ? deg_in : deg_out;
        const float* T = first ? T_in : T_out;
        float dr = deg[row];
        float dc = deg[col];
        float norm = (dr > 0.f ? rsqrtf(dr) : 0.f) * (dc > 0.f ? rsqrtf(dc) : 0.f);
        float c = 0.5f * norm;
        if (c != 0.f) {
            float v0 = c * T[t * D + lane];
            float v1 = c * T[t * D + 64 + lane];
            long b = (long)row * D;
            atomicAdd(&out[b + lane], v0);
            atomicAdd(&out[b + 64 + lane], v1);
        }
    }
}

__global__ void bn_stats_kernel(const float* __restrict__ h, int nent,
                                float* __restrict__ sums, float* __restrict__ sumsq) {
    int col = threadIdx.x;
    float s = 0.f, s2 = 0.f;
    for (int r = blockIdx.x; r < nent; r += gridDim.x) {
        float v = h[(long)r * D + col];
        s += v;
        s2 += v * v;
    }
    atomicAdd(&sums[col], s);
    atomicAdd(&sumsq[col], s2);
}

// ---------------- BN apply (both paths) ----------------

__global__ void bn_apply_kernel(float* __restrict__ h,
                                const float* __restrict__ sums, const float* __restrict__ sumsq,
                                const float* __restrict__ gamma, const float* __restrict__ beta,
                                int nent) {
    long total = ((long)nent * D) / 4;     // in float4 units
    long stride = (long)gridDim.x * blockDim.x;
    float inv_n = 1.0f / (float)nent;
    float4* h4 = (float4*)h;
    for (long i = (long)blockIdx.x * blockDim.x + threadIdx.x; i < total; i += stride) {
        int c0 = (int)((i * 4) & (D - 1));
        float4 v = h4[i];
        float r[4] = {v.x, v.y, v.z, v.w};
#pragma unroll
        for (int j = 0; j < 4; ++j) {
            int col = c0 + j;
            float mean = sums[col] * inv_n;
            float var = sumsq[col] * inv_n - mean * mean;
            float istd = rsqrtf(var + 1e-5f);
            r[j] = tanhf((r[j] - mean) * istd * gamma[col] + beta[col]);
        }
        h4[i] = make_float4(r[0], r[1], r[2], r[3]);
    }
}

extern "C" void kernel_launch(void* const* d_in, const int* in_sizes, int n_in,
                              void* d_out, int out_size, void* d_ws, size_t ws_size,
                              hipStream_t stream) {
    const float* rel_embed     = (const float*)d_in[0];
    const float* rel_embed_in  = (const float*)d_in[1];
    const float* rel_embed_out = (const float*)d_in[2];
    const float* w_in          = (const float*)d_in[3];
    const float* w_out         = (const float*)d_in[4];
    const float* bn_gamma      = (const float*)d_in[5];
    const float* bn_beta       = (const float*)d_in[6];
    const int*   edge_index    = (const int*)d_in[7];
    const int*   edge_type     = (const int*)d_in[8];

    const int nrel = in_sizes[0] / D;               // 500
    const int E2   = in_sizes[8];                   // 3,000,000
    const int E    = E2 / 2;                        // 1,500,000
    const int nent = (out_size - in_sizes[0]) / D;  // 200,000
    const int ntiles = (nent + TILE - 1) / TILE;    // 196

    float* out = (float*)d_out;  // [nent*D] res, then [nrel*D] rel_embed

    const int* rows = edge_index;        // edge_index[0, :]
    const int* cols = edge_index + E2;   // edge_index[1, :]

    // ---- workspace layout (fast path) ----
    float*        ws      = (float*)d_ws;
    float*        deg_in  = ws;                                   // nent
    float*        deg_out = deg_in + nent;                        // nent
    unsigned int* cursor  = (unsigned int*)(deg_out + nent);      // nent
    float*        sums    = (float*)(cursor + nent);              // D
    float*        sumsq   = sums + D;                             // D
    unsigned int* base    = (unsigned int*)(sumsq + D);           // nent+1
    unsigned int* tile_sums = base + nent + 1;                    // ntiles
    unsigned int* tile_off  = tile_sums + ntiles;                 // ntiles
    float*        T_all   = (float*)(tile_off + ntiles);          // 2*nrel*D
    uintptr_t pal = ((uintptr_t)(T_all + (size_t)2 * nrel * D) + 7) & ~(uintptr_t)7;
    uint2*        payload = (uint2*)pal;                          // 2E
    size_t needed = (pal + (size_t)E2 * sizeof(uint2)) - (uintptr_t)d_ws;

    if (needed <= ws_size && ntiles <= 1024) {
        // ---------- fast sort-based path ----------
        float* T_in  = T_all;
        float* T_out = T_all + (size_t)nrel * D;

        hipMemsetAsync(deg_in, 0, ((size_t)3 * nent + 2 * D) * sizeof(float), stream);

        transform_kernel<<<nrel, D, 0, stream>>>(rel_embed_in,  w_in,  T_in,  nrel);
        transform_kernel<<<nrel, D, 0, stream>>>(rel_embed_out, w_out, T_out, nrel);

        degree_kernel<<<2048, 256, 0, stream>>>(edge_index, E, deg_in, deg_out);

        tile_sum_kernel<<<ntiles, 256, 0, stream>>>(deg_in, deg_out, tile_sums, nent);
        scan_tiles_kernel<<<1, 1024, 0, stream>>>(tile_sums, tile_off, base, ntiles, nent);
        base_write_kernel<<<ntiles, 256, 0, stream>>>(deg_in, deg_out, tile_off, base, nent);

        build_kernel<<<2048, 256, 0, stream>>>(rows, cols, edge_type, deg_in, deg_out,
                                               base, cursor, payload, E, nrel);
        accum_kernel<<<2048, 256, 0, stream>>>(base, payload, T_all, out, sums, sumsq, nent);
        bn_apply_kernel<<<4096, 256, 0, stream>>>(out, sums, sumsq, bn_gamma, bn_beta, nent);
    } else {
        // ---------- fallback atomic path ----------
        float* f_deg_in  = ws;
        float* f_deg_out = f_deg_in + nent;
        float* f_T_in    = f_deg_out + nent;
        float* f_T_out   = f_T_in + (size_t)nrel * D;
        float* f_sums    = f_T_out + (size_t)nrel * D;
        float* f_sumsq   = f_sums + D;

        hipMemsetAsync(out, 0, (size_t)nent * D * sizeof(float), stream);
        hipMemsetAsync(f_deg_in, 0, (size_t)2 * nent * sizeof(float), stream);
        hipMemsetAsync(f_sums, 0, (size_t)2 * D * sizeof(float), stream);

        transform_kernel<<<nrel, D, 0, stream>>>(rel_embed_in,  w_in,  f_T_in,  nrel);
        transform_kernel<<<nrel, D, 0, stream>>>(rel_embed_out, w_out, f_T_out, nrel);
        degree_kernel<<<2048, 256, 0, stream>>>(edge_index, E, f_deg_in, f_deg_out);
        scatter_kernel<<<2048, 256, 0, stream>>>(rows, cols, edge_type, f_deg_in, f_deg_out,
                                                 f_T_in, f_T_out, out, E);
        bn_stats_kernel<<<1024, D, 0, stream>>>(out, nent, f_sums, f_sumsq);
        bn_apply_kernel<<<4096, 256, 0, stream>>>(out, f_sums, f_sumsq, bn_gamma, bn_beta, nent);
    }

    // passthrough rel_embed as second tuple output
    hipMemcpyAsync(out + (size_t)nent * D, rel_embed,
                   (size_t)nrel * D * sizeof(float), hipMemcpyDeviceToDevice, stream);
}

// Round 4
// 560.576 us; speedup vs baseline: 2.7316x; 1.1375x over previous
//
#include <hip/hip_runtime.h>

#define D 128
#define TILE 1024

// ---------------- shared small kernels ----------------

// T = R @ W  for one matrix (nrel x D) @ (D x D)
__global__ void transform_kernel(const float* __restrict__ R, const float* __restrict__ W,
                                 float* __restrict__ T, int nrel) {
    __shared__ float row[D];
    int r = blockIdx.x;
    if (r >= nrel) return;
    int t = threadIdx.x; // 0..127
    row[t] = R[r * D + t];
    __syncthreads();
    float acc = 0.f;
#pragma unroll 8
    for (int k = 0; k < D; ++k) acc += row[k] * W[k * D + t];
    T[r * D + t] = acc;
}

// degree counts: rows[0:E] -> deg_in, rows[E:2E] -> deg_out
__global__ void degree_kernel(const int* __restrict__ rows, int E,
                              float* __restrict__ deg_in, float* __restrict__ deg_out) {
    int i = blockIdx.x * blockDim.x + threadIdx.x;
    int stride = gridDim.x * blockDim.x;
    int total = 2 * E;
    for (; i < total; i += stride) {
        int r = rows[i];
        if (i < E) atomicAdd(&deg_in[r], 1.0f);
        else       atomicAdd(&deg_out[r], 1.0f);
    }
}

// deg -> deg^-1/2 in place (covers deg_in and deg_out contiguously)
__global__ __launch_bounds__(256) void dinv_kernel(float* __restrict__ deg, int n) {
    int i = blockIdx.x * blockDim.x + threadIdx.x;
    int stride = gridDim.x * blockDim.x;
    for (; i < n; i += stride) {
        float d = deg[i];
        deg[i] = d > 0.f ? rsqrtf(d) : 0.f;
    }
}

// ---------------- device-wide scan (3 kernels) ----------------

__global__ __launch_bounds__(256) void tile_sum_kernel(
        const float* __restrict__ deg_in, const float* __restrict__ deg_out,
        unsigned int* __restrict__ tile_sums, int nent) {
    int tid = threadIdx.x;
    int i0 = blockIdx.x * TILE + tid * 4;
    unsigned int s = 0;
#pragma unroll
    for (int k = 0; k < 4; ++k) {
        int i = i0 + k;
        if (i < nent) s += (unsigned int)(deg_in[i] + deg_out[i] + 0.5f);
    }
    __shared__ unsigned int ls[256];
    ls[tid] = s;
    __syncthreads();
    for (int off = 128; off >= 1; off >>= 1) {
        if (tid < off) ls[tid] += ls[tid + off];
        __syncthreads();
    }
    if (tid == 0) tile_sums[blockIdx.x] = ls[0];
}

__global__ void scan_tiles_kernel(const unsigned int* __restrict__ tile_sums,
                                  unsigned int* __restrict__ tile_off,
                                  unsigned int* __restrict__ base, int ntiles, int nent) {
    int t = threadIdx.x; // blockDim = 1024
    __shared__ unsigned int ls[1024];
    unsigned int v = (t < ntiles) ? tile_sums[t] : 0u;
    ls[t] = v;
    __syncthreads();
    for (int off = 1; off < 1024; off <<= 1) {
        unsigned int add = (t >= off) ? ls[t - off] : 0u;
        __syncthreads();
        ls[t] += add;
        __syncthreads();
    }
    if (t < ntiles) tile_off[t] = ls[t] - v; // exclusive
    if (t == 1023) base[nent] = ls[1023];    // grand total
}

__global__ __launch_bounds__(256) void base_write_kernel(
        const float* __restrict__ deg_in, const float* __restrict__ deg_out,
        const unsigned int* __restrict__ tile_off,
        unsigned int* __restrict__ base, int nent) {
    int tid = threadIdx.x;
    int i0 = blockIdx.x * TILE + tid * 4;
    unsigned int c[4];
#pragma unroll
    for (int k = 0; k < 4; ++k) {
        int i = i0 + k;
        c[k] = (i < nent) ? (unsigned int)(deg_in[i] + deg_out[i] + 0.5f) : 0u;
    }
    unsigned int s = c[0] + c[1] + c[2] + c[3];
    __shared__ unsigned int ls[256];
    ls[tid] = s;
    __syncthreads();
    for (int off = 1; off < 256; off <<= 1) {
        unsigned int add = (tid >= off) ? ls[tid - off] : 0u;
        __syncthreads();
        ls[tid] += add;
        __syncthreads();
    }
    unsigned int run = (tid > 0 ? ls[tid - 1] : 0u) + tile_off[blockIdx.x];
#pragma unroll
    for (int k = 0; k < 4; ++k) {
        int i = i0 + k;
        if (i < nent) base[i] = run;
        run += c[k];
    }
}

// ---------------- sort-based fast path ----------------

// bucket-scatter: for each edge, payload[pos] = (coeff, table_row)
__global__ void build_kernel(const int* __restrict__ rows, const int* __restrict__ cols,
                             const int* __restrict__ etype,
                             const float* __restrict__ dinv_in, const float* __restrict__ dinv_out,
                             const unsigned int* __restrict__ base, unsigned int* __restrict__ cursor,
                             uint2* __restrict__ payload, int E, int nrel) {
    int i = blockIdx.x * blockDim.x + threadIdx.x;
    int stride = gridDim.x * blockDim.x;
    int total = 2 * E;
    for (; i < total; i += stride) {
        bool first = (i < E);
        int row = rows[i];
        int col = cols[i];
        int t = etype[i];
        const float* dv = first ? dinv_in : dinv_out;
        float c = 0.5f * dv[row] * dv[col];
        unsigned int pos = base[row] + atomicAdd(&cursor[row], 1u);
        payload[pos] = make_uint2(__float_as_uint(c), (unsigned int)(t + (first ? 0 : nrel)));
    }
}

// wave-per-row gather: float4 T loads, 2 edges/iter (half-waves), 2-deep pipeline,
// contiguous row chunks per wave; fused BN partial stats.
__global__ __launch_bounds__(256) void accum_kernel(
        const unsigned int* __restrict__ base, const uint2* __restrict__ payload,
        const float* __restrict__ T_all, float* __restrict__ out,
        float* __restrict__ sums, float* __restrict__ sumsq, int nent) {
    int wave = (blockIdx.x * blockDim.x + threadIdx.x) >> 6;
    int lane = threadIdx.x & 63;
    int half = lane >> 5;   // which edge of the pair
    int l32  = lane & 31;   // float4 group within the 128-float row
    int nw = (gridDim.x * blockDim.x) >> 6;
    int chunk = (nent + nw - 1) / nw;
    int r0 = wave * chunk;
    int r1 = r0 + chunk; if (r1 > nent) r1 = nent;

    float4 s4 = make_float4(0.f, 0.f, 0.f, 0.f);
    float4 q4 = make_float4(0.f, 0.f, 0.f, 0.f);

    for (int row = r0; row < r1; ++row) {
        unsigned int b = base[row], en = base[row + 1];
        float4 a = make_float4(0.f, 0.f, 0.f, 0.f);
        unsigned int i = b + half;
        while (i + 2 < en) {           // two independent chains in flight
            uint2 p0 = payload[i];
            uint2 p1 = payload[i + 2];
            float4 t0 = ((const float4*)(T_all + (size_t)p0.y * D))[l32];
            float4 t1 = ((const float4*)(T_all + (size_t)p1.y * D))[l32];
            float c0 = __uint_as_float(p0.x);
            float c1 = __uint_as_float(p1.x);
            a.x += c0 * t0.x; a.y += c0 * t0.y; a.z += c0 * t0.z; a.w += c0 * t0.w;
            a.x += c1 * t1.x; a.y += c1 * t1.y; a.z += c1 * t1.z; a.w += c1 * t1.w;
            i += 4;
        }
        if (i < en) {
            uint2 p = payload[i];
            float4 t = ((const float4*)(T_all + (size_t)p.y * D))[l32];
            float c = __uint_as_float(p.x);
            a.x += c * t.x; a.y += c * t.y; a.z += c * t.z; a.w += c * t.w;
        }
        // combine the two half-wave partial sums
        a.x += __shfl(a.x, lane ^ 32, 64);
        a.y += __shfl(a.y, lane ^ 32, 64);
        a.z += __shfl(a.z, lane ^ 32, 64);
        a.w += __shfl(a.w, lane ^ 32, 64);
        if (half == 0) {
            ((float4*)(out + (size_t)row * D))[l32] = a;
            s4.x += a.x; s4.y += a.y; s4.z += a.z; s4.w += a.w;
            q4.x += a.x * a.x; q4.y += a.y * a.y; q4.z += a.z * a.z; q4.w += a.w * a.w;
        }
    }

    __shared__ float ls[D], lq[D];
    if (threadIdx.x < D) { ls[threadIdx.x] = 0.f; lq[threadIdx.x] = 0.f; }
    __syncthreads();
    if (half == 0) {
        atomicAdd(&ls[4 * l32 + 0], s4.x); atomicAdd(&ls[4 * l32 + 1], s4.y);
        atomicAdd(&ls[4 * l32 + 2], s4.z); atomicAdd(&ls[4 * l32 + 3], s4.w);
        atomicAdd(&lq[4 * l32 + 0], q4.x); atomicAdd(&lq[4 * l32 + 1], q4.y);
        atomicAdd(&lq[4 * l32 + 2], q4.z); atomicAdd(&lq[4 * l32 + 3], q4.w);
    }
    __syncthreads();
    if (threadIdx.x < D) {
        atomicAdd(&sums[threadIdx.x], ls[threadIdx.x]);
        atomicAdd(&sumsq[threadIdx.x], lq[threadIdx.x]);
    }
}

// ---------------- fallback (atomic) path kernels ----------------

__global__ void scatter_kernel(const int* __restrict__ rows, const int* __restrict__ cols,
                               const int* __restrict__ etype,
                               const float* __restrict__ deg_in, const float* __restrict__ deg_out,
                               const float* __restrict__ T_in, const float* __restrict__ T_out,
                               float* __restrict__ out, int E) {
    int wave = (blockIdx.x * blockDim.x + threadIdx.x) >> 6;
    int lane = threadIdx.x & 63;
    int nwaves = (gridDim.x * blockDim.x) >> 6;
    int total = 2 * E;
    for (int e = wave; e < total; e += nwaves) {
        bool first = (e < E);
        int row = rows[e];
        int col = cols[e];
        int t = etype[e];
        const float* deg = first ? deg_in : deg_out;
        const float* T = first ? T_in : T_out;
        float dr = deg[row];
        float dc = deg[col];
        float norm = (dr > 0.f ? rsqrtf(dr) : 0.f) * (dc > 0.f ? rsqrtf(dc) : 0.f);
        float c = 0.5f * norm;
        if (c != 0.f) {
            float v0 = c * T[t * D + lane];
            float v1 = c * T[t * D + 64 + lane];
            long b = (long)row * D;
            atomicAdd(&out[b + lane], v0);
            atomicAdd(&out[b + 64 + lane], v1);
        }
    }
}

__global__ void bn_stats_kernel(const float* __restrict__ h, int nent,
                                float* __restrict__ sums, float* __restrict__ sumsq) {
    int col = threadIdx.x;
    float s = 0.f, s2 = 0.f;
    for (int r = blockIdx.x; r < nent; r += gridDim.x) {
        float v = h[(long)r * D + col];
        s += v;
        s2 += v * v;
    }
    atomicAdd(&sums[col], s);
    atomicAdd(&sumsq[col], s2);
}

// ---------------- BN apply (both paths) ----------------

__global__ void bn_apply_kernel(float* __restrict__ h,
                                const float* __restrict__ sums, const float* __restrict__ sumsq,
                                const float* __restrict__ gamma, const float* __restrict__ beta,
                                int nent) {
    long total = ((long)nent * D) / 4;     // in float4 units
    long stride = (long)gridDim.x * blockDim.x;
    float inv_n = 1.0f / (float)nent;
    float4* h4 = (float4*)h;
    for (long i = (long)blockIdx.x * blockDim.x + threadIdx.x; i < total; i += stride) {
        int c0 = (int)((i * 4) & (D - 1));
        float4 v = h4[i];
        float r[4] = {v.x, v.y, v.z, v.w};
#pragma unroll
        for (int j = 0; j < 4; ++j) {
            int col = c0 + j;
            float mean = sums[col] * inv_n;
            float var = sumsq[col] * inv_n - mean * mean;
            float istd = rsqrtf(var + 1e-5f);
            r[j] = tanhf((r[j] - mean) * istd * gamma[col] + beta[col]);
        }
        h4[i] = make_float4(r[0], r[1], r[2], r[3]);
    }
}

extern "C" void kernel_launch(void* const* d_in, const int* in_sizes, int n_in,
                              void* d_out, int out_size, void* d_ws, size_t ws_size,
                              hipStream_t stream) {
    const float* rel_embed     = (const float*)d_in[0];
    const float* rel_embed_in  = (const float*)d_in[1];
    const float* rel_embed_out = (const float*)d_in[2];
    const float* w_in          = (const float*)d_in[3];
    const float* w_out         = (const float*)d_in[4];
    const float* bn_gamma      = (const float*)d_in[5];
    const float* bn_beta       = (const float*)d_in[6];
    const int*   edge_index    = (const int*)d_in[7];
    const int*   edge_type     = (const int*)d_in[8];

    const int nrel = in_sizes[0] / D;               // 500
    const int E2   = in_sizes[8];                   // 3,000,000
    const int E    = E2 / 2;                        // 1,500,000
    const int nent = (out_size - in_sizes[0]) / D;  // 200,000
    const int ntiles = (nent + TILE - 1) / TILE;    // 196

    float* out = (float*)d_out;  // [nent*D] res, then [nrel*D] rel_embed

    const int* rows = edge_index;        // edge_index[0, :]
    const int* cols = edge_index + E2;   // edge_index[1, :]

    // ---- workspace layout (fast path) ----
    float*        ws      = (float*)d_ws;
    float*        deg_in  = ws;                                   // nent
    float*        deg_out = deg_in + nent;                        // nent
    unsigned int* cursor  = (unsigned int*)(deg_out + nent);      // nent
    float*        sums    = (float*)(cursor + nent);              // D
    float*        sumsq   = sums + D;                             // D
    unsigned int* base    = (unsigned int*)(sumsq + D);           // nent+1
    unsigned int* tile_sums = base + nent + 1;                    // ntiles
    unsigned int* tile_off  = tile_sums + ntiles;                 // ntiles
    float*        T_all   = (float*)(tile_off + ntiles);          // 2*nrel*D
    uintptr_t pal = ((uintptr_t)(T_all + (size_t)2 * nrel * D) + 15) & ~(uintptr_t)15;
    uint2*        payload = (uint2*)pal;                          // 2E
    size_t needed = (pal + (size_t)E2 * sizeof(uint2)) - (uintptr_t)d_ws;

    if (needed <= ws_size && ntiles <= 1024) {
        // ---------- fast sort-based path ----------
        float* T_in  = T_all;
        float* T_out = T_all + (size_t)nrel * D;

        hipMemsetAsync(deg_in, 0, ((size_t)3 * nent + 2 * D) * sizeof(float), stream);

        transform_kernel<<<nrel, D, 0, stream>>>(rel_embed_in,  w_in,  T_in,  nrel);
        transform_kernel<<<nrel, D, 0, stream>>>(rel_embed_out, w_out, T_out, nrel);

        degree_kernel<<<2048, 256, 0, stream>>>(edge_index, E, deg_in, deg_out);

        tile_sum_kernel<<<ntiles, 256, 0, stream>>>(deg_in, deg_out, tile_sums, nent);
        scan_tiles_kernel<<<1, 1024, 0, stream>>>(tile_sums, tile_off, base, ntiles, nent);
        base_write_kernel<<<ntiles, 256, 0, stream>>>(deg_in, deg_out, tile_off, base, nent);

        // counts no longer needed -> convert to deg^-1/2 in place (both arrays)
        dinv_kernel<<<512, 256, 0, stream>>>(deg_in, 2 * nent);

        build_kernel<<<2048, 256, 0, stream>>>(rows, cols, edge_type, deg_in, deg_out,
                                               base, cursor, payload, E, nrel);
        accum_kernel<<<2048, 256, 0, stream>>>(base, payload, T_all, out, sums, sumsq, nent);
        bn_apply_kernel<<<4096, 256, 0, stream>>>(out, sums, sumsq, bn_gamma, bn_beta, nent);
    } else {
        // ---------- fallback atomic path ----------
        float* f_deg_in  = ws;
        float* f_deg_out = f_deg_in + nent;
        float* f_T_in    = f_deg_out + nent;
        float* f_T_out   = f_T_in + (size_t)nrel * D;
        float* f_sums    = f_T_out + (size_t)nrel * D;
        float* f_sumsq   = f_sums + D;

        hipMemsetAsync(out, 0, (size_t)nent * D * sizeof(float), stream);
        hipMemsetAsync(f_deg_in, 0, (size_t)2 * nent * sizeof(float), stream);
        hipMemsetAsync(f_sums, 0, (size_t)2 * D * sizeof(float), stream);

        transform_kernel<<<nrel, D, 0, stream>>>(rel_embed_in,  w_in,  f_T_in,  nrel);
        transform_kernel<<<nrel, D, 0, stream>>>(rel_embed_out, w_out, f_T_out, nrel);
        degree_kernel<<<2048, 256, 0, stream>>>(edge_index, E, f_deg_in, f_deg_out);
        scatter_kernel<<<2048, 256, 0, stream>>>(rows, cols, edge_type, f_deg_in, f_deg_out,
                                                 f_T_in, f_T_out, out, E);
        bn_stats_kernel<<<1024, D, 0, stream>>>(out, nent, f_sums, f_sumsq);
        bn_apply_kernel<<<4096, 256, 0, stream>>>(out, f_sums, f_sumsq, bn_gamma, bn_beta, nent);
    }

    // passthrough rel_embed as second tuple output
    hipMemcpyAsync(out + (size_t)nent * D, rel_embed,
                   (size_t)nrel * D * sizeof(float), hipMemcpyDeviceToDevice, stream);
}